// Round 9
// baseline (152.070 us; speedup 1.0000x reference)
//
#include <hip/hip_runtime.h>
#include <cmath>

typedef unsigned short u16;
typedef unsigned int   u32;
typedef __attribute__((ext_vector_type(2))) unsigned uintx2;
typedef __attribute__((ext_vector_type(4))) float    floatx4;
typedef __attribute__((ext_vector_type(4))) unsigned uintx4;
typedef __attribute__((ext_vector_type(8))) __bf16   bf16x8;

#define MFMA16(a, b, c) __builtin_amdgcn_mfma_f32_16x16x32_bf16((a), (b), (c), 0, 0, 0)

__device__ __forceinline__ u16 f2bf(float f) {
    union { float f; u32 u; } v; v.f = f;
    u32 u = v.u;
    return (u16)((u + 0x7FFFu + ((u >> 16) & 1u)) >> 16);   // RNE
}

__device__ __forceinline__ bf16x8 ld_frag(const u16* p) {
    uintx4 t = *(const uintx4*)p;
    return __builtin_bit_cast(bf16x8, t);
}

#if __has_builtin(__builtin_amdgcn_exp2f)
#define EXP2F(x) __builtin_amdgcn_exp2f(x)
#else
#define EXP2F(x) exp2f(x)
#endif

typedef __attribute__((address_space(3))) unsigned       lds_u32;
typedef __attribute__((address_space(1))) const unsigned glb_u32;
__device__ __forceinline__ void gl_lds16(const void* g, void* l) {
    __builtin_amdgcn_global_load_lds((glb_u32*)(uintptr_t)g, (lds_u32*)(uintptr_t)l, 16, 0, 0);
}

// log2(e) and 0.125*log2(e)
#define LOG2E   1.4426950408889634f
#define QSCALE  0.18033688011112043f

// ---------------- fused prep: cast x + Q_ext + K_ext + weight transpose ----------------
// grid 3328: [0,1024) cast_x, [1024,2048) ext_q, [2048,3072) ext_k, [3072,3328) transpose_w
__global__ __launch_bounds__(256) void prep_kernel(
        const float* __restrict__ x, const int* __restrict__ gap_ids,
        const int* __restrict__ dur_ids, const int* __restrict__ amask,
        const float* __restrict__ gap_emb, const float* __restrict__ dur_emb,
        const float* __restrict__ Wq, const float* __restrict__ Wk,
        const float* __restrict__ Wv, const float* __restrict__ Wo,
        u16* __restrict__ Xb, u16* __restrict__ Qe, u16* __restrict__ Ke,
        u16* __restrict__ WqT, u16* __restrict__ WkT,
        u16* __restrict__ WvT, u16* __restrict__ WoT) {
    __shared__ u16 T[64][72];
    int bid = blockIdx.x, tid = threadIdx.x;
    if (bid < 1024) {
        int idx = bid * 256 + tid;
        const float* src = x + (size_t)idx * 8;
        uintx4 o;
        o.x = f2bf(src[0]) | ((u32)f2bf(src[1]) << 16);
        o.y = f2bf(src[2]) | ((u32)f2bf(src[3]) << 16);
        o.z = f2bf(src[4]) | ((u32)f2bf(src[5]) << 16);
        o.w = f2bf(src[6]) | ((u32)f2bf(src[7]) << 16);
        *(uintx4*)(Xb + (size_t)idx * 8) = o;
    } else if (bid < 2048) {
        int ri = (bid - 1024) * 32 + (tid >> 3);    // bh*2048 + l
        int l = ri & 2047;
        int b = ri >> 14;
        int ch = tid & 7;
        int gq = gap_ids[b * 2048 + l];
        u16 lg = f2bf(LOG2E);
        u16 vals[8];
        for (int e = 0; e < 8; e++) {
            int j = ch * 8 + e;
            vals[e] = (j == gq || j == 33) ? lg : (u16)0;
        }
        *(uintx4*)(Qe + (size_t)ri * 128 + (8 + ch) * 8) = *(uintx4*)vals;
    } else if (bid < 3072) {
        int ri = (bid - 2048) * 32 + (tid >> 3);
        int bh = ri >> 11, l = ri & 2047;
        int b = bh >> 3, h = bh & 7;
        int ch = tid & 7;
        int gk = gap_ids[b * 2048 + l];
        int did = dur_ids[b * 2048 + l];
        int msk = amask[b * 2048 + l];
        float kval = msk ? dur_emb[did * 8 + h] : -1e9f;
        u16 vals[8];
        for (int e = 0; e < 8; e++) {
            int j = ch * 8 + e;
            float v;
            if (j <= 32) { int d = j - gk; d = d < 0 ? -d : d; v = gap_emb[d * 8 + h]; }
            else if (j == 33) v = kval;
            else v = 0.f;
            vals[e] = f2bf(v);
        }
        int phys = 8 | (ch ^ (l & 7));
        *(uintx4*)(Ke + (size_t)ri * 128 + phys * 8) = *(uintx4*)vals;
    } else {
        int bid2 = bid - 3072;
        int mat = bid2 >> 6, t8 = bid2 & 63;
        int n0 = (t8 & 7) * 64, k0 = (t8 >> 3) * 64;
        const float* W = (mat == 0) ? Wq : (mat == 1) ? Wk : (mat == 2) ? Wv : Wo;
        u16* WT = (mat == 0) ? WqT : (mat == 1) ? WkT : (mat == 2) ? WvT : WoT;
        int r = tid >> 4, cq = tid & 15;
        for (int rr = 0; rr < 4; rr++) {
            int row = r + rr * 16;
            floatx4 s = *(const floatx4*)&W[(size_t)(k0 + row) * 512 + n0 + cq * 4];
            T[cq * 4 + 0][row] = f2bf(s.x);
            T[cq * 4 + 1][row] = f2bf(s.y);
            T[cq * 4 + 2][row] = f2bf(s.z);
            T[cq * 4 + 3][row] = f2bf(s.w);
        }
        __syncthreads();
        for (int p = 0; p < 2; p++) {
            int idx = p * 256 + tid;
            int c = idx >> 3, ch = idx & 7;
            *(uintx4*)&WT[(size_t)(n0 + c) * 512 + k0 + ch * 8] = *(const uintx4*)&T[c][ch * 8];
        }
    }
}

// ---------------- fused QKV projection GEMM, 128x64 tile, LDS-staged coalesced epilogue ----
// grid (32, 24): mat = gy>>3, head hh = gy&7.
__global__ __launch_bounds__(256) void gemm_qkv(
        const u16* __restrict__ Xb,
        const u16* __restrict__ WqT, const u16* __restrict__ WkT, const u16* __restrict__ WvT,
        const float* __restrict__ bq, const float* __restrict__ bk, const float* __restrict__ bv,
        u16* __restrict__ Qe, u16* __restrict__ Ke, u16* __restrict__ Vt) {
    __shared__ u16 smem[12288];                 // As 8192 | Bs 4096 ; reused as Ot
    u16* As = smem;                             // [128][64]
    u16* Bs = smem + 8192;                      // [64][64]

    int tid = threadIdx.x;
    int m0 = blockIdx.x * 128;
    int gy = blockIdx.y;
    int mat = gy >> 3, hh = gy & 7;
    int ncol0 = hh * 64;
    const u16* Bt = (mat == 0) ? WqT : (mat == 1) ? WkT : WvT;
    const float* bias = (mat == 0) ? bq : (mat == 1) ? bk : bv;

    int lane = tid & 63, w = tid >> 6, lo = lane & 15, hi = lane >> 4;
    int wm = w >> 1, wn = w & 1;
    floatx4 acc[4][2] = {};

    for (int kb = 0; kb < 8; kb++) {
        int k0 = kb * 64;
        __syncthreads();
        for (int it = 0; it < 4; it++) {
            int c = it * 256 + tid;
            int row = c >> 3, ch = c & 7;
            gl_lds16((const char*)Xb + ((size_t)(m0 + row) * 512 + k0) * 2 + ch * 16,
                     (char*)As + c * 16);
        }
        for (int it = 0; it < 2; it++) {
            int c = it * 256 + tid;
            int row = c >> 3, ch = c & 7;
            gl_lds16((const char*)Bt + ((size_t)(ncol0 + row) * 512 + k0) * 2 + ch * 16,
                     (char*)Bs + c * 16);
        }
        __syncthreads();
        for (int s = 0; s < 2; s++) {
            bf16x8 a[4], b[2];
            for (int i = 0; i < 4; i++)
                a[i] = ld_frag(&As[(64 * wm + 16 * i + lo) * 64 + s * 32 + hi * 8]);
            for (int j = 0; j < 2; j++)
                b[j] = ld_frag(&Bs[(32 * wn + 16 * j + lo) * 64 + s * 32 + hi * 8]);
            for (int i = 0; i < 4; i++)
                for (int j = 0; j < 2; j++)
                    acc[i][j] = MFMA16(a[i], b[j], acc[i][j]);
        }
    }

    int bb = m0 >> 11, l0 = m0 & 2047;
    __syncthreads();                            // done with As/Bs; reuse as Ot

    if (mat < 2) {
        u16* Ot = smem;                         // [128][pitch 72]
        for (int j = 0; j < 2; j++) {
            int col = 32 * wn + 16 * j + lo;
            float bval = bias[ncol0 + col];
            for (int i = 0; i < 4; i++) {
                int row = 64 * wm + 16 * i + 4 * hi;
                for (int r = 0; r < 4; r++) {
                    float v = acc[i][j][r] + bval;
                    if (mat == 0) v *= QSCALE;
                    Ot[(row + r) * 72 + col] = f2bf(v);
                }
            }
        }
        __syncthreads();
        for (int p = 0; p < 4; p++) {
            int cc = p * 256 + tid;
            int row = cc >> 3, ch = cc & 7;
            int lrow = l0 + row;
            size_t rowi = (size_t)(bb * 8 + hh) * 2048 + lrow;
            int ch2 = (mat == 1) ? (ch ^ (lrow & 7)) : ch;
            u16* dstp = (mat == 0) ? Qe : Ke;
            *(uintx4*)(dstp + rowi * 128 + ch2 * 8) = *(const uintx4*)(Ot + row * 72 + ch * 8);
        }
    } else {
        // V: stage transposed [dc][kl]; stream 16B chunks in PV-fragment order:
        // key = 32g+16p+4q+r -> chunk m_log = 4g+q (content [p*4+r]), m_phys = m_log ^ (dc&7)
        u16* Ot = smem;                         // [64][pitch 136]
        for (int j = 0; j < 2; j++) {
            int dc = 32 * wn + 16 * j + lo;
            float bval = bias[ncol0 + dc];
            for (int i = 0; i < 4; i++) {
                int row = 64 * wm + 16 * i + 4 * hi;
                for (int r = 0; r < 4; r++)
                    Ot[dc * 136 + row + r] = f2bf(acc[i][j][r] + bval);
            }
        }
        __syncthreads();
        for (int p = 0; p < 4; p++) {
            int cc4 = p * 256 + tid;            // (dc 0..63) x (16B chunk 0..15)
            int dc = cc4 >> 4, c16 = cc4 & 15;
            int g64 = c16 >> 3, phys = c16 & 7;
            int mlog = phys ^ (dc & 7);
            int g = mlog >> 2, q = mlog & 3;
            int base = g64 * 64 + 32 * g + 4 * q;
            uintx2 lo4 = *(const uintx2*)(Ot + dc * 136 + base);
            uintx2 hi4 = *(const uintx2*)(Ot + dc * 136 + base + 16);
            uintx4 t; t.x = lo4.x; t.y = lo4.y; t.z = hi4.x; t.w = hi4.y;
            size_t dst = ((size_t)(bb * 8 + hh) * 64 + dc) * 2048 + l0 + g64 * 64 + phys * 8;
            *(uintx4*)(Vt + dst) = t;
        }
    }
}

// ---------------- flash attention: 256 queries/block (4 groups), single-buffer staging ----
// grid (8, 16, 4); block 256 = 4 waves; group g: queries qt4*256 + g*64 + 16w + lo
__global__ __launch_bounds__(256, 2) void flash_attn(
        const u16* __restrict__ Qe, const u16* __restrict__ Ke, const u16* __restrict__ Vt,
        float* __restrict__ Opart, float* __restrict__ Lpart) {
    __shared__ u16 Ks[64 * 128];   // 16 KB
    __shared__ u16 Vs[64 * 64];    // 8 KB

    int tid = threadIdx.x, lane = tid & 63, w = tid >> 6, lo = lane & 15, hi = lane >> 4;
    int qt4 = blockIdx.x, bh = blockIdx.y, sp = blockIdx.z;
    int sw = lo & 7;

    bf16x8 bq_[4][4];
    for (int g = 0; g < 4; g++) {
        size_t qrow = ((size_t)bh * 2048 + qt4 * 256 + g * 64 + 16 * w + lo) * 128;
        for (int kc = 0; kc < 4; kc++) bq_[g][kc] = ld_frag(&Qe[qrow + kc * 32 + hi * 8]);
    }

    floatx4 O[4][4] = {};       // O[g][u][r]: group g, query 4hi+r, d=16u+lo
    floatx4 Lacc[4] = {};
    uintx4 onesu; onesu.x = 0x3F803F80u; onesu.y = 0x3F803F80u; onesu.z = 0x3F803F80u; onesu.w = 0x3F803F80u;
    bf16x8 ones = __builtin_bit_cast(bf16x8, onesu);

    const u16* KeB = Ke + (size_t)bh * 2048 * 128;
    const u16* VtB = Vt + (size_t)bh * 64 * 2048;

    int kbeg = sp * 8, kend = kbeg + 8;

    for (int kt = kbeg; kt < kend; kt++) {
        int k0 = kt * 64;
        __syncthreads();                        // previous iteration's reads done
        {   // K_ext tile: 16 KB contiguous
            const char* gk = (const char*)(KeB + (size_t)k0 * 128);
            for (int r2 = 0; r2 < 4; r2++)
                gl_lds16(gk + r2 * 4096 + tid * 16, (char*)Ks + r2 * 4096 + tid * 16);
        }
        {   // V tile: 64 d-rows x 128 B
            for (int p2 = 0; p2 < 2; p2++) {
                int c = p2 * 256 + tid;
                int row = c >> 3, ch = c & 7;
                gl_lds16((const char*)(VtB + (size_t)row * 2048 + k0) + ch * 16,
                         (char*)Vs + c * 16);
            }
        }
        __syncthreads();                        // DMA drained (each wave waits own vmcnt)

        // S^T = K * Q^T per t-tile; exp+pack immediately (keeps sf live range short)
        u32 pk[4][4][2];                        // [g][t][pair]
        for (int t = 0; t < 4; t++) {
            const u16* krow = &Ks[(16 * t + lo) * 128];
            bf16x8 a[4];
            for (int kc = 0; kc < 4; kc++) {
                int cc = kc * 4 + hi;
                int pc = (cc & 8) | ((cc & 7) ^ sw);
                a[kc] = ld_frag(&krow[pc * 8]);
            }
            floatx4 sf[4] = {};
            for (int kc = 0; kc < 4; kc++) {
                sf[0] = MFMA16(a[kc], bq_[0][kc], sf[0]);
                sf[1] = MFMA16(a[kc], bq_[1][kc], sf[1]);
                sf[2] = MFMA16(a[kc], bq_[2][kc], sf[2]);
                sf[3] = MFMA16(a[kc], bq_[3][kc], sf[3]);
            }
            for (int g = 0; g < 4; g++) {
                float p0 = EXP2F(sf[g][0]);
                float p1 = EXP2F(sf[g][1]);
                float p2 = EXP2F(sf[g][2]);
                float p3 = EXP2F(sf[g][3]);
                u32 u0 = __builtin_bit_cast(u32, p0) + 0x8000u;
                u32 u1 = __builtin_bit_cast(u32, p1) + 0x8000u;
                u32 u2 = __builtin_bit_cast(u32, p2) + 0x8000u;
                u32 u3 = __builtin_bit_cast(u32, p3) + 0x8000u;
                pk[g][t][0] = __builtin_amdgcn_perm(u1, u0, 0x07060302);
                pk[g][t][1] = __builtin_amdgcn_perm(u3, u2, 0x07060302);
            }
        }

        // O += P V (V frags shared across all groups) ; l via ones-MFMA
        for (int tp = 0; tp < 2; tp++) {
            bf16x8 af[4];
            for (int g = 0; g < 4; g++) {
                uintx4 av;
                av.x = pk[g][2 * tp][0]; av.y = pk[g][2 * tp][1];
                av.z = pk[g][2 * tp + 1][0]; av.w = pk[g][2 * tp + 1][1];
                af[g] = __builtin_bit_cast(bf16x8, av);
            }
            Lacc[0] = MFMA16(af[0], ones, Lacc[0]);
            Lacc[1] = MFMA16(af[1], ones, Lacc[1]);
            Lacc[2] = MFMA16(af[2], ones, Lacc[2]);
            Lacc[3] = MFMA16(af[3], ones, Lacc[3]);
            for (int u = 0; u < 4; u++) {
                const u16* vrow = &Vs[(16 * u + lo) * 64];
                int m = (4 * tp + hi) ^ sw;
                bf16x8 bv = ld_frag(&vrow[m * 8]);
                O[0][u] = MFMA16(af[0], bv, O[0][u]);
                O[1][u] = MFMA16(af[1], bv, O[1][u]);
                O[2][u] = MFMA16(af[2], bv, O[2][u]);
                O[3][u] = MFMA16(af[3], bv, O[3][u]);
            }
        }
    }

    for (int g = 0; g < 4; g++) {
        int qt = 4 * qt4 + g;
        size_t obase = (((size_t)sp * 16 + bh) * 32 + qt) * 4096;
        for (int u = 0; u < 4; u++)
            for (int r = 0; r < 4; r++)
                Opart[obase + (size_t)(16 * w + 4 * hi + r) * 64 + 16 * u + lo] = O[g][u][r];
        if (lo == 0) {
            size_t lbase = (((size_t)sp * 16 + bh) * 32 + qt) * 64;
            for (int r = 0; r < 4; r++) Lpart[lbase + 16 * w + 4 * hi + r] = Lacc[g][r];
        }
    }
}

// ---------------- combine the 4 key-splits, normalize, cast to bf16 (vectorized) ----------------
__global__ __launch_bounds__(256) void combine_kernel(const float* __restrict__ Opart,
                                                      const float* __restrict__ Lpart,
                                                      u16* __restrict__ Ob) {
    int idx = blockIdx.x * 256 + threadIdx.x;   // 0..524287, 4 floats each
    int d4 = idx & 15;
    int q = (idx >> 4) & 2047;
    int bh = idx >> 15;
    int qt = q >> 6, qr = q & 63;
    size_t b0 = ((size_t)bh * 32 + qt) * 4096 + qr * 64 + d4 * 4;
    floatx4 o0 = *(const floatx4*)&Opart[b0];
    floatx4 o1 = *(const floatx4*)&Opart[b0 + 2097152];
    floatx4 o2 = *(const floatx4*)&Opart[b0 + 4194304];
    floatx4 o3 = *(const floatx4*)&Opart[b0 + 6291456];
    size_t lb = ((size_t)bh * 32 + qt) * 64 + qr;
    float rl = 1.0f / (Lpart[lb] + Lpart[lb + 32768] + Lpart[lb + 65536] + Lpart[lb + 98304]);
    uintx2 pk2;
    pk2.x = f2bf((o0.x + o1.x + o2.x + o3.x) * rl) | ((u32)f2bf((o0.y + o1.y + o2.y + o3.y) * rl) << 16);
    pk2.y = f2bf((o0.z + o1.z + o2.z + o3.z) * rl) | ((u32)f2bf((o0.w + o1.w + o2.w + o3.w) * rl) << 16);
    int bb = bh >> 3, h = bh & 7;
    *(uintx2*)&Ob[((size_t)(bb * 2048 + q)) * 512 + h * 64 + d4 * 4] = pk2;
}

// ---------------- output projection GEMM, 64x64 tile (bf16 in, fp32 out) ----------------
__global__ __launch_bounds__(256) void gemm_out(
        const u16* __restrict__ Ob, const u16* __restrict__ WoT,
        const float* __restrict__ bo, float* __restrict__ out) {
    __shared__ u16 As[64][72];
    __shared__ u16 Bs[64][72];
    int tid = threadIdx.x;
    int m0 = blockIdx.x * 64;
    int n0 = blockIdx.y * 64;
    int lane = tid & 63, w = tid >> 6, lo = lane & 15, hi = lane >> 4;
    floatx4 acc[4] = {};

    for (int kb = 0; kb < 8; kb++) {
        __syncthreads();
        for (int c = tid; c < 512; c += 256) {
            int row = c >> 3, cc = c & 7;
            *(uintx4*)&As[row][cc * 8] =
                *(const uintx4*)&Ob[(size_t)(m0 + row) * 512 + kb * 64 + cc * 8];
            *(uintx4*)&Bs[row][cc * 8] =
                *(const uintx4*)&WoT[(size_t)(n0 + row) * 512 + kb * 64 + cc * 8];
        }
        __syncthreads();
        for (int s = 0; s < 2; s++) {
            bf16x8 a = ld_frag(&As[16 * w + lo][8 * hi + 32 * s]);
            for (int t = 0; t < 4; t++) {
                bf16x8 b = ld_frag(&Bs[16 * t + lo][8 * hi + 32 * s]);
                acc[t] = MFMA16(a, b, acc[t]);
            }
        }
    }
    for (int t = 0; t < 4; t++) {
        int n = n0 + 16 * t + lo;
        float bval = bo[n];
        for (int r = 0; r < 4; r++) {
            int mrow = m0 + 16 * w + 4 * hi + r;
            out[(size_t)mrow * 512 + n] = acc[t][r] + bval;
        }
    }
}

extern "C" void kernel_launch(void* const* d_in, const int* in_sizes, int n_in,
                              void* d_out, int out_size, void* d_ws, size_t ws_size,
                              hipStream_t stream) {
    const float* x     = (const float*)d_in[0];
    const int*   amask = (const int*)d_in[1];
    const int*   gids  = (const int*)d_in[2];
    const int*   dids  = (const int*)d_in[3];
    const float* Wq    = (const float*)d_in[4];
    const float* bq    = (const float*)d_in[5];
    const float* Wk    = (const float*)d_in[6];
    const float* bk    = (const float*)d_in[7];
    const float* Wv    = (const float*)d_in[8];
    const float* bv    = (const float*)d_in[9];
    const float* Wo    = (const float*)d_in[10];
    const float* bo    = (const float*)d_in[11];
    const float* gap_emb = (const float*)d_in[12];
    const float* dur_emb = (const float*)d_in[13];
    float* out = (float*)d_out;

    char* ws = (char*)d_ws;
    u16*   Qe    = (u16*)(ws + 0);            // 8.4 MB
    u16*   Ke    = (u16*)(ws + 8388608);      // 8.4 MB
    u16*   Vt    = (u16*)(ws + 16777216);     // 4.2 MB
    float* Opart = (float*)(ws + 20971520);   // 33.6 MB (4 splits)
    float* Lpart = (float*)(ws + 54525952);   // 0.52 MB
    u16*   Ob    = (u16*)(ws + 55050240);     // 4.2 MB
    u16*   WoT   = (u16*)(ws + 59244544);     // 0.5 MB
    // stage-1 scratch aliased inside Opart (dead before flash_attn writes it)
    u16*   Xb    = (u16*)(ws + 20971520);     // 4.2 MB
    u16*   WqT   = (u16*)(ws + 25165824);
    u16*   WkT   = (u16*)(ws + 25690112);
    u16*   WvT   = (u16*)(ws + 26214400);

    hipLaunchKernelGGL(prep_kernel, dim3(3328), dim3(256), 0, stream,
                       x, gids, dids, amask, gap_emb, dur_emb,
                       Wq, Wk, Wv, Wo, Xb, Qe, Ke, WqT, WkT, WvT, WoT);
    hipLaunchKernelGGL(gemm_qkv, dim3(32, 24), dim3(256), 0, stream,
                       Xb, WqT, WkT, WvT, bq, bk, bv, Qe, Ke, Vt);
    hipLaunchKernelGGL(flash_attn, dim3(8, 16, 4), dim3(256), 0, stream,
                       Qe, Ke, Vt, Opart, Lpart);
    hipLaunchKernelGGL(combine_kernel, dim3(2048), dim3(256), 0, stream,
                       Opart, Lpart, Ob);
    hipLaunchKernelGGL(gemm_out, dim3(64, 8), dim3(256), 0, stream,
                       Ob, WoT, bo, out);
}

// Round 10
// 148.733 us; speedup vs baseline: 1.0224x; 1.0224x over previous
//
#include <hip/hip_runtime.h>
#include <cmath>

typedef unsigned short u16;
typedef unsigned int   u32;
typedef __attribute__((ext_vector_type(2))) unsigned uintx2;
typedef __attribute__((ext_vector_type(4))) float    floatx4;
typedef __attribute__((ext_vector_type(4))) unsigned uintx4;
typedef __attribute__((ext_vector_type(8))) __bf16   bf16x8;

#define MFMA16(a, b, c) __builtin_amdgcn_mfma_f32_16x16x32_bf16((a), (b), (c), 0, 0, 0)

__device__ __forceinline__ u16 f2bf(float f) {
    union { float f; u32 u; } v; v.f = f;
    u32 u = v.u;
    return (u16)((u + 0x7FFFu + ((u >> 16) & 1u)) >> 16);   // RNE
}

__device__ __forceinline__ bf16x8 ld_frag(const u16* p) {
    uintx4 t = *(const uintx4*)p;
    return __builtin_bit_cast(bf16x8, t);
}

#if __has_builtin(__builtin_amdgcn_exp2f)
#define EXP2F(x) __builtin_amdgcn_exp2f(x)
#else
#define EXP2F(x) exp2f(x)
#endif

typedef __attribute__((address_space(3))) unsigned       lds_u32;
typedef __attribute__((address_space(1))) const unsigned glb_u32;
__device__ __forceinline__ void gl_lds16(const void* g, void* l) {
    __builtin_amdgcn_global_load_lds((glb_u32*)(uintptr_t)g, (lds_u32*)(uintptr_t)l, 16, 0, 0);
}

// log2(e) and 0.125*log2(e)
#define LOG2E   1.4426950408889634f
#define QSCALE  0.18033688011112043f

// ---------------- fused prep: cast x + Q_ext + K_ext + weight transpose ----------------
// grid 3328: [0,1024) cast_x, [1024,2048) ext_q, [2048,3072) ext_k, [3072,3328) transpose_w
__global__ __launch_bounds__(256) void prep_kernel(
        const float* __restrict__ x, const int* __restrict__ gap_ids,
        const int* __restrict__ dur_ids, const int* __restrict__ amask,
        const float* __restrict__ gap_emb, const float* __restrict__ dur_emb,
        const float* __restrict__ Wq, const float* __restrict__ Wk,
        const float* __restrict__ Wv, const float* __restrict__ Wo,
        u16* __restrict__ Xb, u16* __restrict__ Qe, u16* __restrict__ Ke,
        u16* __restrict__ WqT, u16* __restrict__ WkT,
        u16* __restrict__ WvT, u16* __restrict__ WoT) {
    __shared__ u16 T[64][72];
    int bid = blockIdx.x, tid = threadIdx.x;
    if (bid < 1024) {
        int idx = bid * 256 + tid;
        const float* src = x + (size_t)idx * 8;
        uintx4 o;
        o.x = f2bf(src[0]) | ((u32)f2bf(src[1]) << 16);
        o.y = f2bf(src[2]) | ((u32)f2bf(src[3]) << 16);
        o.z = f2bf(src[4]) | ((u32)f2bf(src[5]) << 16);
        o.w = f2bf(src[6]) | ((u32)f2bf(src[7]) << 16);
        *(uintx4*)(Xb + (size_t)idx * 8) = o;
    } else if (bid < 2048) {
        int ri = (bid - 1024) * 32 + (tid >> 3);    // bh*2048 + l
        int l = ri & 2047;
        int b = ri >> 14;
        int ch = tid & 7;
        int gq = gap_ids[b * 2048 + l];
        u16 lg = f2bf(LOG2E);
        u16 vals[8];
        for (int e = 0; e < 8; e++) {
            int j = ch * 8 + e;
            vals[e] = (j == gq || j == 33) ? lg : (u16)0;
        }
        *(uintx4*)(Qe + (size_t)ri * 128 + (8 + ch) * 8) = *(uintx4*)vals;
    } else if (bid < 3072) {
        int ri = (bid - 2048) * 32 + (tid >> 3);
        int bh = ri >> 11, l = ri & 2047;
        int b = bh >> 3, h = bh & 7;
        int ch = tid & 7;
        int gk = gap_ids[b * 2048 + l];
        int did = dur_ids[b * 2048 + l];
        int msk = amask[b * 2048 + l];
        float kval = msk ? dur_emb[did * 8 + h] : -1e9f;
        u16 vals[8];
        for (int e = 0; e < 8; e++) {
            int j = ch * 8 + e;
            float v;
            if (j <= 32) { int d = j - gk; d = d < 0 ? -d : d; v = gap_emb[d * 8 + h]; }
            else if (j == 33) v = kval;
            else v = 0.f;
            vals[e] = f2bf(v);
        }
        int phys = 8 | (ch ^ (l & 7));
        *(uintx4*)(Ke + (size_t)ri * 128 + phys * 8) = *(uintx4*)vals;
    } else {
        int bid2 = bid - 3072;
        int mat = bid2 >> 6, t8 = bid2 & 63;
        int n0 = (t8 & 7) * 64, k0 = (t8 >> 3) * 64;
        const float* W = (mat == 0) ? Wq : (mat == 1) ? Wk : (mat == 2) ? Wv : Wo;
        u16* WT = (mat == 0) ? WqT : (mat == 1) ? WkT : (mat == 2) ? WvT : WoT;
        int r = tid >> 4, cq = tid & 15;
        for (int rr = 0; rr < 4; rr++) {
            int row = r + rr * 16;
            floatx4 s = *(const floatx4*)&W[(size_t)(k0 + row) * 512 + n0 + cq * 4];
            T[cq * 4 + 0][row] = f2bf(s.x);
            T[cq * 4 + 1][row] = f2bf(s.y);
            T[cq * 4 + 2][row] = f2bf(s.z);
            T[cq * 4 + 3][row] = f2bf(s.w);
        }
        __syncthreads();
        for (int p = 0; p < 2; p++) {
            int idx = p * 256 + tid;
            int c = idx >> 3, ch = idx & 7;
            *(uintx4*)&WT[(size_t)(n0 + c) * 512 + k0 + ch * 8] = *(const uintx4*)&T[c][ch * 8];
        }
    }
}

// ---------------- fused QKV projection GEMM, 128x64 tile, LDS-staged coalesced epilogue ----
// grid (32, 24): mat = gy>>3, head hh = gy&7.
__global__ __launch_bounds__(256) void gemm_qkv(
        const u16* __restrict__ Xb,
        const u16* __restrict__ WqT, const u16* __restrict__ WkT, const u16* __restrict__ WvT,
        const float* __restrict__ bq, const float* __restrict__ bk, const float* __restrict__ bv,
        u16* __restrict__ Qe, u16* __restrict__ Ke, u16* __restrict__ Vt) {
    __shared__ u16 smem[12288];                 // As 8192 | Bs 4096 ; reused as Ot
    u16* As = smem;                             // [128][64]
    u16* Bs = smem + 8192;                      // [64][64]

    int tid = threadIdx.x;
    int m0 = blockIdx.x * 128;
    int gy = blockIdx.y;
    int mat = gy >> 3, hh = gy & 7;
    int ncol0 = hh * 64;
    const u16* Bt = (mat == 0) ? WqT : (mat == 1) ? WkT : WvT;
    const float* bias = (mat == 0) ? bq : (mat == 1) ? bk : bv;

    int lane = tid & 63, w = tid >> 6, lo = lane & 15, hi = lane >> 4;
    int wm = w >> 1, wn = w & 1;
    floatx4 acc[4][2] = {};

    for (int kb = 0; kb < 8; kb++) {
        int k0 = kb * 64;
        __syncthreads();
        for (int it = 0; it < 4; it++) {
            int c = it * 256 + tid;
            int row = c >> 3, ch = c & 7;
            gl_lds16((const char*)Xb + ((size_t)(m0 + row) * 512 + k0) * 2 + ch * 16,
                     (char*)As + c * 16);
        }
        for (int it = 0; it < 2; it++) {
            int c = it * 256 + tid;
            int row = c >> 3, ch = c & 7;
            gl_lds16((const char*)Bt + ((size_t)(ncol0 + row) * 512 + k0) * 2 + ch * 16,
                     (char*)Bs + c * 16);
        }
        __syncthreads();
        for (int s = 0; s < 2; s++) {
            bf16x8 a[4], b[2];
            for (int i = 0; i < 4; i++)
                a[i] = ld_frag(&As[(64 * wm + 16 * i + lo) * 64 + s * 32 + hi * 8]);
            for (int j = 0; j < 2; j++)
                b[j] = ld_frag(&Bs[(32 * wn + 16 * j + lo) * 64 + s * 32 + hi * 8]);
            for (int i = 0; i < 4; i++)
                for (int j = 0; j < 2; j++)
                    acc[i][j] = MFMA16(a[i], b[j], acc[i][j]);
        }
    }

    int bb = m0 >> 11, l0 = m0 & 2047;
    __syncthreads();                            // done with As/Bs; reuse as Ot

    if (mat < 2) {
        u16* Ot = smem;                         // [128][pitch 72]
        for (int j = 0; j < 2; j++) {
            int col = 32 * wn + 16 * j + lo;
            float bval = bias[ncol0 + col];
            for (int i = 0; i < 4; i++) {
                int row = 64 * wm + 16 * i + 4 * hi;
                for (int r = 0; r < 4; r++) {
                    float v = acc[i][j][r] + bval;
                    if (mat == 0) v *= QSCALE;
                    Ot[(row + r) * 72 + col] = f2bf(v);
                }
            }
        }
        __syncthreads();
        for (int p = 0; p < 4; p++) {
            int cc = p * 256 + tid;
            int row = cc >> 3, ch = cc & 7;
            int lrow = l0 + row;
            size_t rowi = (size_t)(bb * 8 + hh) * 2048 + lrow;
            int ch2 = (mat == 1) ? (ch ^ (lrow & 7)) : ch;
            u16* dstp = (mat == 0) ? Qe : Ke;
            *(uintx4*)(dstp + rowi * 128 + ch2 * 8) = *(const uintx4*)(Ot + row * 72 + ch * 8);
        }
    } else {
        // V: stage transposed [dc][kl]; stream 16B chunks in PV-fragment order:
        // key = 32g+16p+4q+r -> chunk m_log = 4g+q (content [p*4+r]), m_phys = m_log ^ (dc&7)
        u16* Ot = smem;                         // [64][pitch 136]
        for (int j = 0; j < 2; j++) {
            int dc = 32 * wn + 16 * j + lo;
            float bval = bias[ncol0 + dc];
            for (int i = 0; i < 4; i++) {
                int row = 64 * wm + 16 * i + 4 * hi;
                for (int r = 0; r < 4; r++)
                    Ot[dc * 136 + row + r] = f2bf(acc[i][j][r] + bval);
            }
        }
        __syncthreads();
        for (int p = 0; p < 4; p++) {
            int cc4 = p * 256 + tid;            // (dc 0..63) x (16B chunk 0..15)
            int dc = cc4 >> 4, c16 = cc4 & 15;
            int g64 = c16 >> 3, phys = c16 & 7;
            int mlog = phys ^ (dc & 7);
            int g = mlog >> 2, q = mlog & 3;
            int base = g64 * 64 + 32 * g + 4 * q;
            uintx2 lo4 = *(const uintx2*)(Ot + dc * 136 + base);
            uintx2 hi4 = *(const uintx2*)(Ot + dc * 136 + base + 16);
            uintx4 t; t.x = lo4.x; t.y = lo4.y; t.z = hi4.x; t.w = hi4.y;
            size_t dst = ((size_t)(bb * 8 + hh) * 64 + dc) * 2048 + l0 + g64 * 64 + phys * 8;
            *(uintx4*)(Vt + dst) = t;
        }
    }
}

// ---------------- flash attention: 256 queries/block (4 groups), async dbuf + explicit drain
// grid (8, 16, 4); block 256 = 4 waves; group g: queries qt4*256 + g*64 + 16w + lo
__global__ __launch_bounds__(256, 2) void flash_attn(
        const u16* __restrict__ Qe, const u16* __restrict__ Ke, const u16* __restrict__ Vt,
        float* __restrict__ Opart, float* __restrict__ Lpart) {
    __shared__ u16 Ks[2][64 * 128];   // 2 x 16 KB
    __shared__ u16 Vs[2][64 * 64];    // 2 x 8 KB

    int tid = threadIdx.x, lane = tid & 63, w = tid >> 6, lo = lane & 15, hi = lane >> 4;
    int qt4 = blockIdx.x, bh = blockIdx.y, sp = blockIdx.z;
    int sw = lo & 7;

    bf16x8 bq_[4][4];
    for (int g = 0; g < 4; g++) {
        size_t qrow = ((size_t)bh * 2048 + qt4 * 256 + g * 64 + 16 * w + lo) * 128;
        for (int kc = 0; kc < 4; kc++) bq_[g][kc] = ld_frag(&Qe[qrow + kc * 32 + hi * 8]);
    }

    floatx4 O[4][4] = {};       // O[g][u][r]: group g, query 4hi+r, d=16u+lo
    floatx4 Lacc[4] = {};
    uintx4 onesu; onesu.x = 0x3F803F80u; onesu.y = 0x3F803F80u; onesu.z = 0x3F803F80u; onesu.w = 0x3F803F80u;
    bf16x8 ones = __builtin_bit_cast(bf16x8, onesu);

    const u16* KeB = Ke + (size_t)bh * 2048 * 128;
    const u16* VtB = Vt + (size_t)bh * 64 * 2048;

    int kbeg = sp * 8, kend = kbeg + 8;

#define STAGE(KT, BUF) do {                                                        \
        int k0_ = (KT) * 64;                                                       \
        const char* gk_ = (const char*)(KeB + (size_t)k0_ * 128);                  \
        char* lk_ = (char*)Ks[BUF];                                                \
        for (int r2 = 0; r2 < 4; r2++)                                             \
            gl_lds16(gk_ + r2 * 4096 + tid * 16, lk_ + r2 * 4096 + tid * 16);      \
        for (int p2 = 0; p2 < 2; p2++) {                                           \
            int c_ = p2 * 256 + tid;                                               \
            int row_ = c_ >> 3, ch_ = c_ & 7;                                      \
            gl_lds16((const char*)(VtB + (size_t)row_ * 2048 + k0_) + ch_ * 16,    \
                     (char*)Vs[BUF] + c_ * 16);                                    \
        }                                                                          \
    } while (0)

    int cur = 0;
    STAGE(kbeg, 0);
    for (int kt = kbeg; kt < kend; kt++) {
        // guarantee this wave's outstanding global_load_lds DMAs (for buf[cur])
        // have landed before the barrier — the compiler cannot see this dependency
        // through the laundered LDS pointers, so make it explicit.
        asm volatile("s_waitcnt vmcnt(0)" ::: "memory");
        __syncthreads();
        if (kt + 1 < kend) STAGE(kt + 1, cur ^ 1);

        const u16* Ksc = Ks[cur];
        const u16* Vsc = Vs[cur];

        // S^T = K * Q^T per t-tile; exp+pack immediately (short sf live range)
        u32 pk[4][4][2];                        // [g][t][pair]
        for (int t = 0; t < 4; t++) {
            const u16* krow = &Ksc[(16 * t + lo) * 128];
            bf16x8 a[4];
            for (int kc = 0; kc < 4; kc++) {
                int cc = kc * 4 + hi;
                int pc = (cc & 8) | ((cc & 7) ^ sw);
                a[kc] = ld_frag(&krow[pc * 8]);
            }
            floatx4 sf[4] = {};
            for (int kc = 0; kc < 4; kc++) {
                sf[0] = MFMA16(a[kc], bq_[0][kc], sf[0]);
                sf[1] = MFMA16(a[kc], bq_[1][kc], sf[1]);
                sf[2] = MFMA16(a[kc], bq_[2][kc], sf[2]);
                sf[3] = MFMA16(a[kc], bq_[3][kc], sf[3]);
            }
            for (int g = 0; g < 4; g++) {
                float p0 = EXP2F(sf[g][0]);
                float p1 = EXP2F(sf[g][1]);
                float p2 = EXP2F(sf[g][2]);
                float p3 = EXP2F(sf[g][3]);
                u32 u0 = __builtin_bit_cast(u32, p0) + 0x8000u;
                u32 u1 = __builtin_bit_cast(u32, p1) + 0x8000u;
                u32 u2 = __builtin_bit_cast(u32, p2) + 0x8000u;
                u32 u3 = __builtin_bit_cast(u32, p3) + 0x8000u;
                pk[g][t][0] = __builtin_amdgcn_perm(u1, u0, 0x07060302);
                pk[g][t][1] = __builtin_amdgcn_perm(u3, u2, 0x07060302);
            }
        }

        // O += P V (V frags shared across all groups) ; l via ones-MFMA
        for (int tp = 0; tp < 2; tp++) {
            bf16x8 af[4];
            for (int g = 0; g < 4; g++) {
                uintx4 av;
                av.x = pk[g][2 * tp][0]; av.y = pk[g][2 * tp][1];
                av.z = pk[g][2 * tp + 1][0]; av.w = pk[g][2 * tp + 1][1];
                af[g] = __builtin_bit_cast(bf16x8, av);
            }
            Lacc[0] = MFMA16(af[0], ones, Lacc[0]);
            Lacc[1] = MFMA16(af[1], ones, Lacc[1]);
            Lacc[2] = MFMA16(af[2], ones, Lacc[2]);
            Lacc[3] = MFMA16(af[3], ones, Lacc[3]);
            for (int u = 0; u < 4; u++) {
                const u16* vrow = &Vsc[(16 * u + lo) * 64];
                int m = (4 * tp + hi) ^ sw;
                bf16x8 bv = ld_frag(&vrow[m * 8]);
                O[0][u] = MFMA16(af[0], bv, O[0][u]);
                O[1][u] = MFMA16(af[1], bv, O[1][u]);
                O[2][u] = MFMA16(af[2], bv, O[2][u]);
                O[3][u] = MFMA16(af[3], bv, O[3][u]);
            }
        }
        cur ^= 1;
    }
#undef STAGE

    for (int g = 0; g < 4; g++) {
        int qt = 4 * qt4 + g;
        size_t obase = (((size_t)sp * 16 + bh) * 32 + qt) * 4096;
        for (int u = 0; u < 4; u++)
            for (int r = 0; r < 4; r++)
                Opart[obase + (size_t)(16 * w + 4 * hi + r) * 64 + 16 * u + lo] = O[g][u][r];
        if (lo == 0) {
            size_t lbase = (((size_t)sp * 16 + bh) * 32 + qt) * 64;
            for (int r = 0; r < 4; r++) Lpart[lbase + 16 * w + 4 * hi + r] = Lacc[g][r];
        }
    }
}

// ---------------- combine the 4 key-splits, normalize, cast to bf16 (vectorized) ----------------
__global__ __launch_bounds__(256) void combine_kernel(const float* __restrict__ Opart,
                                                      const float* __restrict__ Lpart,
                                                      u16* __restrict__ Ob) {
    int idx = blockIdx.x * 256 + threadIdx.x;   // 0..524287, 4 floats each
    int d4 = idx & 15;
    int q = (idx >> 4) & 2047;
    int bh = idx >> 15;
    int qt = q >> 6, qr = q & 63;
    size_t b0 = ((size_t)bh * 32 + qt) * 4096 + qr * 64 + d4 * 4;
    floatx4 o0 = *(const floatx4*)&Opart[b0];
    floatx4 o1 = *(const floatx4*)&Opart[b0 + 2097152];
    floatx4 o2 = *(const floatx4*)&Opart[b0 + 4194304];
    floatx4 o3 = *(const floatx4*)&Opart[b0 + 6291456];
    size_t lb = ((size_t)bh * 32 + qt) * 64 + qr;
    float rl = 1.0f / (Lpart[lb] + Lpart[lb + 32768] + Lpart[lb + 65536] + Lpart[lb + 98304]);
    uintx2 pk2;
    pk2.x = f2bf((o0.x + o1.x + o2.x + o3.x) * rl) | ((u32)f2bf((o0.y + o1.y + o2.y + o3.y) * rl) << 16);
    pk2.y = f2bf((o0.z + o1.z + o2.z + o3.z) * rl) | ((u32)f2bf((o0.w + o1.w + o2.w + o3.w) * rl) << 16);
    int bb = bh >> 3, h = bh & 7;
    *(uintx2*)&Ob[((size_t)(bb * 2048 + q)) * 512 + h * 64 + d4 * 4] = pk2;
}

// ---------------- output projection GEMM, 64x64 tile (bf16 in, fp32 out) ----------------
__global__ __launch_bounds__(256) void gemm_out(
        const u16* __restrict__ Ob, const u16* __restrict__ WoT,
        const float* __restrict__ bo, float* __restrict__ out) {
    __shared__ u16 As[64][72];
    __shared__ u16 Bs[64][72];
    int tid = threadIdx.x;
    int m0 = blockIdx.x * 64;
    int n0 = blockIdx.y * 64;
    int lane = tid & 63, w = tid >> 6, lo = lane & 15, hi = lane >> 4;
    floatx4 acc[4] = {};

    for (int kb = 0; kb < 8; kb++) {
        __syncthreads();
        for (int c = tid; c < 512; c += 256) {
            int row = c >> 3, cc = c & 7;
            *(uintx4*)&As[row][cc * 8] =
                *(const uintx4*)&Ob[(size_t)(m0 + row) * 512 + kb * 64 + cc * 8];
            *(uintx4*)&Bs[row][cc * 8] =
                *(const uintx4*)&WoT[(size_t)(n0 + row) * 512 + kb * 64 + cc * 8];
        }
        __syncthreads();
        for (int s = 0; s < 2; s++) {
            bf16x8 a = ld_frag(&As[16 * w + lo][8 * hi + 32 * s]);
            for (int t = 0; t < 4; t++) {
                bf16x8 b = ld_frag(&Bs[16 * t + lo][8 * hi + 32 * s]);
                acc[t] = MFMA16(a, b, acc[t]);
            }
        }
    }
    for (int t = 0; t < 4; t++) {
        int n = n0 + 16 * t + lo;
        float bval = bo[n];
        for (int r = 0; r < 4; r++) {
            int mrow = m0 + 16 * w + 4 * hi + r;
            out[(size_t)mrow * 512 + n] = acc[t][r] + bval;
        }
    }
}

extern "C" void kernel_launch(void* const* d_in, const int* in_sizes, int n_in,
                              void* d_out, int out_size, void* d_ws, size_t ws_size,
                              hipStream_t stream) {
    const float* x     = (const float*)d_in[0];
    const int*   amask = (const int*)d_in[1];
    const int*   gids  = (const int*)d_in[2];
    const int*   dids  = (const int*)d_in[3];
    const float* Wq    = (const float*)d_in[4];
    const float* bq    = (const float*)d_in[5];
    const float* Wk    = (const float*)d_in[6];
    const float* bk    = (const float*)d_in[7];
    const float* Wv    = (const float*)d_in[8];
    const float* bv    = (const float*)d_in[9];
    const float* Wo    = (const float*)d_in[10];
    const float* bo    = (const float*)d_in[11];
    const float* gap_emb = (const float*)d_in[12];
    const float* dur_emb = (const float*)d_in[13];
    float* out = (float*)d_out;

    char* ws = (char*)d_ws;
    u16*   Qe    = (u16*)(ws + 0);            // 8.4 MB
    u16*   Ke    = (u16*)(ws + 8388608);      // 8.4 MB
    u16*   Vt    = (u16*)(ws + 16777216);     // 4.2 MB
    float* Opart = (float*)(ws + 20971520);   // 33.6 MB (4 splits)
    float* Lpart = (float*)(ws + 54525952);   // 0.52 MB
    u16*   Ob    = (u16*)(ws + 55050240);     // 4.2 MB
    u16*   WoT   = (u16*)(ws + 59244544);     // 0.5 MB
    // stage-1 scratch aliased inside Opart (dead before flash_attn writes it)
    u16*   Xb    = (u16*)(ws + 20971520);     // 4.2 MB
    u16*   WqT   = (u16*)(ws + 25165824);
    u16*   WkT   = (u16*)(ws + 25690112);
    u16*   WvT   = (u16*)(ws + 26214400);

    hipLaunchKernelGGL(prep_kernel, dim3(3328), dim3(256), 0, stream,
                       x, gids, dids, amask, gap_emb, dur_emb,
                       Wq, Wk, Wv, Wo, Xb, Qe, Ke, WqT, WkT, WvT, WoT);
    hipLaunchKernelGGL(gemm_qkv, dim3(32, 24), dim3(256), 0, stream,
                       Xb, WqT, WkT, WvT, bq, bk, bv, Qe, Ke, Vt);
    hipLaunchKernelGGL(flash_attn, dim3(8, 16, 4), dim3(256), 0, stream,
                       Qe, Ke, Vt, Opart, Lpart);
    hipLaunchKernelGGL(combine_kernel, dim3(2048), dim3(256), 0, stream,
                       Opart, Lpart, Ob);
    hipLaunchKernelGGL(gemm_out, dim3(64, 8), dim3(256), 0, stream,
                       Ob, WoT, bo, out);
}

// Round 11
// 141.912 us; speedup vs baseline: 1.0716x; 1.0481x over previous
//
#include <hip/hip_runtime.h>
#include <cmath>

typedef unsigned short u16;
typedef unsigned int   u32;
typedef __attribute__((ext_vector_type(2))) unsigned uintx2;
typedef __attribute__((ext_vector_type(4))) float    floatx4;
typedef __attribute__((ext_vector_type(4))) unsigned uintx4;
typedef __attribute__((ext_vector_type(8))) __bf16   bf16x8;

#define MFMA16(a, b, c) __builtin_amdgcn_mfma_f32_16x16x32_bf16((a), (b), (c), 0, 0, 0)

__device__ __forceinline__ u16 f2bf(float f) {
    union { float f; u32 u; } v; v.f = f;
    u32 u = v.u;
    return (u16)((u + 0x7FFFu + ((u >> 16) & 1u)) >> 16);   // RNE
}

__device__ __forceinline__ bf16x8 ld_frag(const u16* p) {
    uintx4 t = *(const uintx4*)p;
    return __builtin_bit_cast(bf16x8, t);
}

#if __has_builtin(__builtin_amdgcn_exp2f)
#define EXP2F(x) __builtin_amdgcn_exp2f(x)
#else
#define EXP2F(x) exp2f(x)
#endif

typedef __attribute__((address_space(3))) unsigned       lds_u32;
typedef __attribute__((address_space(1))) const unsigned glb_u32;
__device__ __forceinline__ void gl_lds16(const void* g, void* l) {
    __builtin_amdgcn_global_load_lds((glb_u32*)(uintptr_t)g, (lds_u32*)(uintptr_t)l, 16, 0, 0);
}

// explicit drain: the compiler cannot see the DMA->ds_read dependency through
// the laundered LDS pointers, so the wait before each barrier must be manual.
#define DRAIN() asm volatile("s_waitcnt vmcnt(0)" ::: "memory")

// log2(e) and 0.125*log2(e)
#define LOG2E   1.4426950408889634f
#define QSCALE  0.18033688011112043f

// ---------------- fused prep: cast x + Q_ext + K_ext + weight transpose ----------------
// grid 3328: [0,1024) cast_x, [1024,2048) ext_q, [2048,3072) ext_k, [3072,3328) transpose_w
__global__ __launch_bounds__(256) void prep_kernel(
        const float* __restrict__ x, const int* __restrict__ gap_ids,
        const int* __restrict__ dur_ids, const int* __restrict__ amask,
        const float* __restrict__ gap_emb, const float* __restrict__ dur_emb,
        const float* __restrict__ Wq, const float* __restrict__ Wk,
        const float* __restrict__ Wv, const float* __restrict__ Wo,
        u16* __restrict__ Xb, u16* __restrict__ Qe, u16* __restrict__ Ke,
        u16* __restrict__ WqT, u16* __restrict__ WkT,
        u16* __restrict__ WvT, u16* __restrict__ WoT) {
    __shared__ u16 T[64][72];
    int bid = blockIdx.x, tid = threadIdx.x;
    if (bid < 1024) {
        int idx = bid * 256 + tid;
        const float* src = x + (size_t)idx * 8;
        uintx4 o;
        o.x = f2bf(src[0]) | ((u32)f2bf(src[1]) << 16);
        o.y = f2bf(src[2]) | ((u32)f2bf(src[3]) << 16);
        o.z = f2bf(src[4]) | ((u32)f2bf(src[5]) << 16);
        o.w = f2bf(src[6]) | ((u32)f2bf(src[7]) << 16);
        *(uintx4*)(Xb + (size_t)idx * 8) = o;
    } else if (bid < 2048) {
        int ri = (bid - 1024) * 32 + (tid >> 3);    // bh*2048 + l
        int l = ri & 2047;
        int b = ri >> 14;
        int ch = tid & 7;
        int gq = gap_ids[b * 2048 + l];
        u16 lg = f2bf(LOG2E);
        u16 vals[8];
        for (int e = 0; e < 8; e++) {
            int j = ch * 8 + e;
            vals[e] = (j == gq || j == 33) ? lg : (u16)0;
        }
        *(uintx4*)(Qe + (size_t)ri * 128 + (8 + ch) * 8) = *(uintx4*)vals;
    } else if (bid < 3072) {
        int ri = (bid - 2048) * 32 + (tid >> 3);
        int bh = ri >> 11, l = ri & 2047;
        int b = bh >> 3, h = bh & 7;
        int ch = tid & 7;
        int gk = gap_ids[b * 2048 + l];
        int did = dur_ids[b * 2048 + l];
        int msk = amask[b * 2048 + l];
        float kval = msk ? dur_emb[did * 8 + h] : -1e9f;
        u16 vals[8];
        for (int e = 0; e < 8; e++) {
            int j = ch * 8 + e;
            float v;
            if (j <= 32) { int d = j - gk; d = d < 0 ? -d : d; v = gap_emb[d * 8 + h]; }
            else if (j == 33) v = kval;
            else v = 0.f;
            vals[e] = f2bf(v);
        }
        int phys = 8 | (ch ^ (l & 7));
        *(uintx4*)(Ke + (size_t)ri * 128 + phys * 8) = *(uintx4*)vals;
    } else {
        int bid2 = bid - 3072;
        int mat = bid2 >> 6, t8 = bid2 & 63;
        int n0 = (t8 & 7) * 64, k0 = (t8 >> 3) * 64;
        const float* W = (mat == 0) ? Wq : (mat == 1) ? Wk : (mat == 2) ? Wv : Wo;
        u16* WT = (mat == 0) ? WqT : (mat == 1) ? WkT : (mat == 2) ? WvT : WoT;
        int r = tid >> 4, cq = tid & 15;
        for (int rr = 0; rr < 4; rr++) {
            int row = r + rr * 16;
            floatx4 s = *(const floatx4*)&W[(size_t)(k0 + row) * 512 + n0 + cq * 4];
            T[cq * 4 + 0][row] = f2bf(s.x);
            T[cq * 4 + 1][row] = f2bf(s.y);
            T[cq * 4 + 2][row] = f2bf(s.z);
            T[cq * 4 + 3][row] = f2bf(s.w);
        }
        __syncthreads();
        for (int p = 0; p < 2; p++) {
            int idx = p * 256 + tid;
            int c = idx >> 3, ch = idx & 7;
            *(uintx4*)&WT[(size_t)(n0 + c) * 512 + k0 + ch * 8] = *(const uintx4*)&T[c][ch * 8];
        }
    }
}

// ---------------- fused QKV projection GEMM, 128x64 tile, async dbuf, coalesced epilogue ----
// grid (32, 24): mat = gy>>3, head hh = gy&7.
__global__ __launch_bounds__(256) void gemm_qkv(
        const u16* __restrict__ Xb,
        const u16* __restrict__ WqT, const u16* __restrict__ WkT, const u16* __restrict__ WvT,
        const float* __restrict__ bq, const float* __restrict__ bk, const float* __restrict__ bv,
        u16* __restrict__ Qe, u16* __restrict__ Ke, u16* __restrict__ Vt) {
    __shared__ u16 smem[2][12288];              // per buf: As[0:8192) | Bs[8192:12288)

    int tid = threadIdx.x;
    int m0 = blockIdx.x * 128;
    int gy = blockIdx.y;
    int mat = gy >> 3, hh = gy & 7;
    int ncol0 = hh * 64;
    const u16* Bt = (mat == 0) ? WqT : (mat == 1) ? WkT : WvT;
    const float* bias = (mat == 0) ? bq : (mat == 1) ? bk : bv;

    int lane = tid & 63, w = tid >> 6, lo = lane & 15, hi = lane >> 4;
    int wm = w >> 1, wn = w & 1;
    floatx4 acc[4][2] = {};

#define QSTAGE(KB, BUF) do {                                                            \
        int k0_ = (KB) * 64;                                                            \
        for (int it = 0; it < 4; it++) {                                                \
            int c = it * 256 + tid;                                                     \
            int row = c >> 3, ch = c & 7;                                               \
            gl_lds16((const char*)Xb + ((size_t)(m0 + row) * 512 + k0_) * 2 + ch * 16,  \
                     (char*)(smem[BUF]) + c * 16);                                      \
        }                                                                               \
        for (int it = 0; it < 2; it++) {                                                \
            int c = it * 256 + tid;                                                     \
            int row = c >> 3, ch = c & 7;                                               \
            gl_lds16((const char*)Bt + ((size_t)(ncol0 + row) * 512 + k0_) * 2 + ch * 16,\
                     (char*)(smem[BUF] + 8192) + c * 16);                               \
        }                                                                               \
    } while (0)

    QSTAGE(0, 0);
    for (int kb = 0; kb < 8; kb++) {
        DRAIN();
        __syncthreads();
        if (kb + 1 < 8) QSTAGE(kb + 1, (kb + 1) & 1);
        const u16* As = smem[kb & 1];
        const u16* Bs = smem[kb & 1] + 8192;
        for (int s = 0; s < 2; s++) {
            bf16x8 a[4], b[2];
            for (int i = 0; i < 4; i++)
                a[i] = ld_frag(&As[(64 * wm + 16 * i + lo) * 64 + s * 32 + hi * 8]);
            for (int j = 0; j < 2; j++)
                b[j] = ld_frag(&Bs[(32 * wn + 16 * j + lo) * 64 + s * 32 + hi * 8]);
            for (int i = 0; i < 4; i++)
                for (int j = 0; j < 2; j++)
                    acc[i][j] = MFMA16(a[i], b[j], acc[i][j]);
        }
    }
#undef QSTAGE

    int bb = m0 >> 11, l0 = m0 & 2047;
    __syncthreads();                            // all waves past last compute

    if (mat < 2) {
        u16* Ot = smem[0];                      // [128][pitch 72]
        for (int j = 0; j < 2; j++) {
            int col = 32 * wn + 16 * j + lo;
            float bval = bias[ncol0 + col];
            for (int i = 0; i < 4; i++) {
                int row = 64 * wm + 16 * i + 4 * hi;
                for (int r = 0; r < 4; r++) {
                    float v = acc[i][j][r] + bval;
                    if (mat == 0) v *= QSCALE;
                    Ot[(row + r) * 72 + col] = f2bf(v);
                }
            }
        }
        __syncthreads();
        for (int p = 0; p < 4; p++) {
            int cc = p * 256 + tid;
            int row = cc >> 3, ch = cc & 7;
            int lrow = l0 + row;
            size_t rowi = (size_t)(bb * 8 + hh) * 2048 + lrow;
            int ch2 = (mat == 1) ? (ch ^ (lrow & 7)) : ch;
            u16* dstp = (mat == 0) ? Qe : Ke;
            *(uintx4*)(dstp + rowi * 128 + ch2 * 8) = *(const uintx4*)(Ot + row * 72 + ch * 8);
        }
    } else {
        // V: stage transposed [dc][kl]; stream 16B chunks in PV-fragment order:
        // key = 32g+16p+4q+r -> chunk m_log = 4g+q (content [p*4+r]), m_phys = m_log ^ (dc&7)
        u16* Ot = smem[0];                      // [64][pitch 136]
        for (int j = 0; j < 2; j++) {
            int dc = 32 * wn + 16 * j + lo;
            float bval = bias[ncol0 + dc];
            for (int i = 0; i < 4; i++) {
                int row = 64 * wm + 16 * i + 4 * hi;
                for (int r = 0; r < 4; r++)
                    Ot[dc * 136 + row + r] = f2bf(acc[i][j][r] + bval);
            }
        }
        __syncthreads();
        for (int p = 0; p < 4; p++) {
            int cc4 = p * 256 + tid;            // (dc 0..63) x (16B chunk 0..15)
            int dc = cc4 >> 4, c16 = cc4 & 15;
            int g64 = c16 >> 3, phys = c16 & 7;
            int mlog = phys ^ (dc & 7);
            int g = mlog >> 2, q = mlog & 3;
            int base = g64 * 64 + 32 * g + 4 * q;
            uintx2 lo4 = *(const uintx2*)(Ot + dc * 136 + base);
            uintx2 hi4 = *(const uintx2*)(Ot + dc * 136 + base + 16);
            uintx4 t; t.x = lo4.x; t.y = lo4.y; t.z = hi4.x; t.w = hi4.y;
            size_t dst = ((size_t)(bb * 8 + hh) * 64 + dc) * 2048 + l0 + g64 * 64 + phys * 8;
            *(uintx4*)(Vt + dst) = t;
        }
    }
}

// ---------------- flash attention: 128 queries/block, shared K/V frags, async dbuf + drain
// grid (16, 16, 2); block 256 = 4 waves
__global__ __launch_bounds__(256, 3) void flash_attn(
        const u16* __restrict__ Qe, const u16* __restrict__ Ke, const u16* __restrict__ Vt,
        float* __restrict__ Opart, float* __restrict__ Lpart) {
    __shared__ u16 Ks[2][64 * 128];   // 2 x 16 KB
    __shared__ u16 Vs[2][64 * 64];    // 2 x 8 KB

    int tid = threadIdx.x, lane = tid & 63, w = tid >> 6, lo = lane & 15, hi = lane >> 4;
    int qt2 = blockIdx.x, bh = blockIdx.y, sp = blockIdx.z;
    int sw = lo & 7;

    bf16x8 bq_[2][4];
    for (int g = 0; g < 2; g++) {
        size_t qrow = ((size_t)bh * 2048 + qt2 * 128 + g * 64 + 16 * w + lo) * 128;
        for (int kc = 0; kc < 4; kc++) bq_[g][kc] = ld_frag(&Qe[qrow + kc * 32 + hi * 8]);
    }

    floatx4 O[2][4] = {};       // O[g][u][r]: query grp g (4hi+r), d=16u+lo
    floatx4 Lacc[2] = {};
    uintx4 onesu; onesu.x = 0x3F803F80u; onesu.y = 0x3F803F80u; onesu.z = 0x3F803F80u; onesu.w = 0x3F803F80u;
    bf16x8 ones = __builtin_bit_cast(bf16x8, onesu);

    const u16* KeB = Ke + (size_t)bh * 2048 * 128;
    const u16* VtB = Vt + (size_t)bh * 64 * 2048;

    int kbeg = sp * 16, kend = kbeg + 16;

#define STAGE(KT, BUF) do {                                                        \
        int k0_ = (KT) * 64;                                                       \
        const char* gk_ = (const char*)(KeB + (size_t)k0_ * 128);                  \
        char* lk_ = (char*)Ks[BUF];                                                \
        for (int r2 = 0; r2 < 4; r2++)                                             \
            gl_lds16(gk_ + r2 * 4096 + tid * 16, lk_ + r2 * 4096 + tid * 16);      \
        for (int p2 = 0; p2 < 2; p2++) {                                           \
            int c_ = p2 * 256 + tid;                                               \
            int row_ = c_ >> 3, ch_ = c_ & 7;                                      \
            gl_lds16((const char*)(VtB + (size_t)row_ * 2048 + k0_) + ch_ * 16,    \
                     (char*)Vs[BUF] + c_ * 16);                                    \
        }                                                                          \
    } while (0)

    int cur = 0;
    STAGE(kbeg, 0);
    for (int kt = kbeg; kt < kend; kt++) {
        DRAIN();                                // buf[cur]'s DMAs guaranteed landed
        __syncthreads();
        if (kt + 1 < kend) STAGE(kt + 1, cur ^ 1);

        const u16* Ksc = Ks[cur];
        const u16* Vsc = Vs[cur];

        // S^T = K * Q^T for both query groups (K frags shared)
        floatx4 sf[2][4] = {};
        for (int t = 0; t < 4; t++) {
            const u16* krow = &Ksc[(16 * t + lo) * 128];
            for (int kc = 0; kc < 4; kc++) {
                int cc = kc * 4 + hi;
                int pc = (cc & 8) | ((cc & 7) ^ sw);
                bf16x8 a = ld_frag(&krow[pc * 8]);
                sf[0][t] = MFMA16(a, bq_[0][kc], sf[0][t]);
                sf[1][t] = MFMA16(a, bq_[1][kc], sf[1][t]);
            }
        }

        // P = 2^S, pack to bf16 (round-half-up); af[g][tp] = A-frags
        bf16x8 af[2][2];
        for (int g = 0; g < 2; g++) {
            u32 pk[4][2];
            for (int t = 0; t < 4; t++) {
                float p0 = EXP2F(sf[g][t][0]);
                float p1 = EXP2F(sf[g][t][1]);
                float p2 = EXP2F(sf[g][t][2]);
                float p3 = EXP2F(sf[g][t][3]);
                u32 u0 = __builtin_bit_cast(u32, p0) + 0x8000u;
                u32 u1 = __builtin_bit_cast(u32, p1) + 0x8000u;
                u32 u2 = __builtin_bit_cast(u32, p2) + 0x8000u;
                u32 u3 = __builtin_bit_cast(u32, p3) + 0x8000u;
                pk[t][0] = __builtin_amdgcn_perm(u1, u0, 0x07060302);
                pk[t][1] = __builtin_amdgcn_perm(u3, u2, 0x07060302);
            }
            for (int tp = 0; tp < 2; tp++) {
                uintx4 av;
                av.x = pk[2 * tp][0]; av.y = pk[2 * tp][1];
                av.z = pk[2 * tp + 1][0]; av.w = pk[2 * tp + 1][1];
                af[g][tp] = __builtin_bit_cast(bf16x8, av);
            }
        }

        // O += P V (V frags shared across groups; one b128 per frag) ; l via ones-MFMA
        for (int tp = 0; tp < 2; tp++) {
            Lacc[0] = MFMA16(af[0][tp], ones, Lacc[0]);
            Lacc[1] = MFMA16(af[1][tp], ones, Lacc[1]);
            for (int u = 0; u < 4; u++) {
                const u16* vrow = &Vsc[(16 * u + lo) * 64];
                int m = (4 * tp + hi) ^ sw;
                bf16x8 bv = ld_frag(&vrow[m * 8]);
                O[0][u] = MFMA16(af[0][tp], bv, O[0][u]);
                O[1][u] = MFMA16(af[1][tp], bv, O[1][u]);
            }
        }
        cur ^= 1;
    }
#undef STAGE

    for (int g = 0; g < 2; g++) {
        int qt = 2 * qt2 + g;
        size_t obase = (((size_t)sp * 16 + bh) * 32 + qt) * 4096;
        for (int u = 0; u < 4; u++)
            for (int r = 0; r < 4; r++)
                Opart[obase + (size_t)(16 * w + 4 * hi + r) * 64 + 16 * u + lo] = O[g][u][r];
        if (lo == 0) {
            size_t lbase = (((size_t)sp * 16 + bh) * 32 + qt) * 64;
            for (int r = 0; r < 4; r++) Lpart[lbase + 16 * w + 4 * hi + r] = Lacc[g][r];
        }
    }
}

// ---------------- combine the 2 key-splits, normalize, cast to bf16 (vectorized) ----------------
__global__ __launch_bounds__(256) void combine_kernel(const float* __restrict__ Opart,
                                                      const float* __restrict__ Lpart,
                                                      u16* __restrict__ Ob) {
    int idx = blockIdx.x * 256 + threadIdx.x;   // 0..524287, 4 floats each
    int d4 = idx & 15;
    int q = (idx >> 4) & 2047;
    int bh = idx >> 15;
    int qt = q >> 6, qr = q & 63;
    size_t b0 = ((size_t)bh * 32 + qt) * 4096 + qr * 64 + d4 * 4;
    floatx4 o0 = *(const floatx4*)&Opart[b0];
    floatx4 o1 = *(const floatx4*)&Opart[b0 + 2097152];
    size_t lb = ((size_t)bh * 32 + qt) * 64 + qr;
    float rl = 1.0f / (Lpart[lb] + Lpart[lb + 32768]);
    uintx2 pk2;
    pk2.x = f2bf((o0.x + o1.x) * rl) | ((u32)f2bf((o0.y + o1.y) * rl) << 16);
    pk2.y = f2bf((o0.z + o1.z) * rl) | ((u32)f2bf((o0.w + o1.w) * rl) << 16);
    int bb = bh >> 3, h = bh & 7;
    *(uintx2*)&Ob[((size_t)(bb * 2048 + q)) * 512 + h * 64 + d4 * 4] = pk2;
}

// ---------------- output projection GEMM, 64x64 tile, async dbuf (bf16 in, fp32 out) ------
__global__ __launch_bounds__(256) void gemm_out(
        const u16* __restrict__ Ob, const u16* __restrict__ WoT,
        const float* __restrict__ bo, float* __restrict__ out) {
    __shared__ u16 smem[2][8192];               // per buf: As[0:4096) | Bs[4096:8192)
    int tid = threadIdx.x;
    int m0 = blockIdx.x * 64;
    int n0 = blockIdx.y * 64;
    int lane = tid & 63, w = tid >> 6, lo = lane & 15, hi = lane >> 4;
    floatx4 acc[4] = {};

#define OSTAGE(KB, BUF) do {                                                            \
        int k0_ = (KB) * 64;                                                            \
        for (int it = 0; it < 2; it++) {                                                \
            int c = it * 256 + tid;                                                     \
            int row = c >> 3, ch = c & 7;                                               \
            gl_lds16((const char*)Ob + ((size_t)(m0 + row) * 512 + k0_) * 2 + ch * 16,  \
                     (char*)(smem[BUF]) + c * 16);                                      \
        }                                                                               \
        for (int it = 0; it < 2; it++) {                                                \
            int c = it * 256 + tid;                                                     \
            int row = c >> 3, ch = c & 7;                                               \
            gl_lds16((const char*)WoT + ((size_t)(n0 + row) * 512 + k0_) * 2 + ch * 16, \
                     (char*)(smem[BUF] + 4096) + c * 16);                               \
        }                                                                               \
    } while (0)

    OSTAGE(0, 0);
    for (int kb = 0; kb < 8; kb++) {
        DRAIN();
        __syncthreads();
        if (kb + 1 < 8) OSTAGE(kb + 1, (kb + 1) & 1);
        const u16* As = smem[kb & 1];
        const u16* Bs = smem[kb & 1] + 4096;
        for (int s = 0; s < 2; s++) {
            bf16x8 a = ld_frag(&As[(16 * w + lo) * 64 + s * 32 + hi * 8]);
            for (int t = 0; t < 4; t++) {
                bf16x8 b = ld_frag(&Bs[(16 * t + lo) * 64 + s * 32 + hi * 8]);
                acc[t] = MFMA16(a, b, acc[t]);
            }
        }
    }
#undef OSTAGE

    for (int t = 0; t < 4; t++) {
        int n = n0 + 16 * t + lo;
        float bval = bo[n];
        for (int r = 0; r < 4; r++) {
            int mrow = m0 + 16 * w + 4 * hi + r;
            out[(size_t)mrow * 512 + n] = acc[t][r] + bval;
        }
    }
}

extern "C" void kernel_launch(void* const* d_in, const int* in_sizes, int n_in,
                              void* d_out, int out_size, void* d_ws, size_t ws_size,
                              hipStream_t stream) {
    const float* x     = (const float*)d_in[0];
    const int*   amask = (const int*)d_in[1];
    const int*   gids  = (const int*)d_in[2];
    const int*   dids  = (const int*)d_in[3];
    const float* Wq    = (const float*)d_in[4];
    const float* bq    = (const float*)d_in[5];
    const float* Wk    = (const float*)d_in[6];
    const float* bk    = (const float*)d_in[7];
    const float* Wv    = (const float*)d_in[8];
    const float* bv    = (const float*)d_in[9];
    const float* Wo    = (const float*)d_in[10];
    const float* bo    = (const float*)d_in[11];
    const float* gap_emb = (const float*)d_in[12];
    const float* dur_emb = (const float*)d_in[13];
    float* out = (float*)d_out;

    char* ws = (char*)d_ws;
    u16*   Qe    = (u16*)(ws + 0);            // 8.4 MB
    u16*   Ke    = (u16*)(ws + 8388608);      // 8.4 MB
    u16*   Vt    = (u16*)(ws + 16777216);     // 4.2 MB
    float* Opart = (float*)(ws + 20971520);   // 16.8 MB (2 splits)
    float* Lpart = (float*)(ws + 37748736);   // 0.26 MB
    u16*   Ob    = (u16*)(ws + 38010880);     // 4.2 MB
    u16*   WoT   = (u16*)(ws + 42205184);     // 0.5 MB
    // stage-1 scratch aliased inside Opart (dead before flash_attn writes it)
    u16*   Xb    = (u16*)(ws + 20971520);     // 4.2 MB
    u16*   WqT   = (u16*)(ws + 25165824);
    u16*   WkT   = (u16*)(ws + 25690112);
    u16*   WvT   = (u16*)(ws + 26214400);

    hipLaunchKernelGGL(prep_kernel, dim3(3328), dim3(256), 0, stream,
                       x, gids, dids, amask, gap_emb, dur_emb,
                       Wq, Wk, Wv, Wo, Xb, Qe, Ke, WqT, WkT, WvT, WoT);
    hipLaunchKernelGGL(gemm_qkv, dim3(32, 24), dim3(256), 0, stream,
                       Xb, WqT, WkT, WvT, bq, bk, bv, Qe, Ke, Vt);
    hipLaunchKernelGGL(flash_attn, dim3(16, 16, 2), dim3(256), 0, stream,
                       Qe, Ke, Vt, Opart, Lpart);
    hipLaunchKernelGGL(combine_kernel, dim3(2048), dim3(256), 0, stream,
                       Opart, Lpart, Ob);
    hipLaunchKernelGGL(gemm_out, dim3(64, 8), dim3(256), 0, stream,
                       Ob, WoT, bo, out);
}

// Round 12
// 140.814 us; speedup vs baseline: 1.0799x; 1.0078x over previous
//
#include <hip/hip_runtime.h>
#include <cmath>

typedef unsigned short u16;
typedef unsigned int   u32;
typedef __attribute__((ext_vector_type(2))) unsigned uintx2;
typedef __attribute__((ext_vector_type(4))) float    floatx4;
typedef __attribute__((ext_vector_type(4))) unsigned uintx4;
typedef __attribute__((ext_vector_type(8))) __bf16   bf16x8;

#define MFMA16(a, b, c) __builtin_amdgcn_mfma_f32_16x16x32_bf16((a), (b), (c), 0, 0, 0)

__device__ __forceinline__ u16 f2bf(float f) {
    union { float f; u32 u; } v; v.f = f;
    u32 u = v.u;
    return (u16)((u + 0x7FFFu + ((u >> 16) & 1u)) >> 16);   // RNE
}
__device__ __forceinline__ float bfhi2f(u32 u) {            // high-16 bf16 -> float
    return __builtin_bit_cast(float, u & 0xFFFF0000u);
}
__device__ __forceinline__ float bflo2f(u32 u) {            // low-16 bf16 -> float
    return __builtin_bit_cast(float, u << 16);
}

__device__ __forceinline__ bf16x8 ld_frag(const u16* p) {
    uintx4 t = *(const uintx4*)p;
    return __builtin_bit_cast(bf16x8, t);
}

#if __has_builtin(__builtin_amdgcn_exp2f)
#define EXP2F(x) __builtin_amdgcn_exp2f(x)
#else
#define EXP2F(x) exp2f(x)
#endif

typedef __attribute__((address_space(3))) unsigned       lds_u32;
typedef __attribute__((address_space(1))) const unsigned glb_u32;
__device__ __forceinline__ void gl_lds16(const void* g, void* l) {
    __builtin_amdgcn_global_load_lds((glb_u32*)(uintptr_t)g, (lds_u32*)(uintptr_t)l, 16, 0, 0);
}

// explicit drain: the compiler cannot see the DMA->ds_read dependency through
// the laundered LDS pointers, so the wait before each barrier must be manual.
#define DRAIN() asm volatile("s_waitcnt vmcnt(0)" ::: "memory")

// log2(e) and 0.125*log2(e)
#define LOG2E   1.4426950408889634f
#define QSCALE  0.18033688011112043f

// ---------------- fused prep: cast x + Q_ext + K_ext + weight transpose ----------------
// grid 3328: [0,1024) cast_x, [1024,2048) ext_q, [2048,3072) ext_k, [3072,3328) transpose_w
__global__ __launch_bounds__(256) void prep_kernel(
        const float* __restrict__ x, const int* __restrict__ gap_ids,
        const int* __restrict__ dur_ids, const int* __restrict__ amask,
        const float* __restrict__ gap_emb, const float* __restrict__ dur_emb,
        const float* __restrict__ Wq, const float* __restrict__ Wk,
        const float* __restrict__ Wv, const float* __restrict__ Wo,
        u16* __restrict__ Xb, u16* __restrict__ Qe, u16* __restrict__ Ke,
        u16* __restrict__ WqT, u16* __restrict__ WkT,
        u16* __restrict__ WvT, u16* __restrict__ WoT) {
    __shared__ u16 T[64][72];
    int bid = blockIdx.x, tid = threadIdx.x;
    if (bid < 1024) {
        int idx = bid * 256 + tid;
        const float* src = x + (size_t)idx * 8;
        uintx4 o;
        o.x = f2bf(src[0]) | ((u32)f2bf(src[1]) << 16);
        o.y = f2bf(src[2]) | ((u32)f2bf(src[3]) << 16);
        o.z = f2bf(src[4]) | ((u32)f2bf(src[5]) << 16);
        o.w = f2bf(src[6]) | ((u32)f2bf(src[7]) << 16);
        *(uintx4*)(Xb + (size_t)idx * 8) = o;
    } else if (bid < 2048) {
        int ri = (bid - 1024) * 32 + (tid >> 3);    // bh*2048 + l
        int l = ri & 2047;
        int b = ri >> 14;
        int ch = tid & 7;
        int gq = gap_ids[b * 2048 + l];
        u16 lg = f2bf(LOG2E);
        u16 vals[8];
        for (int e = 0; e < 8; e++) {
            int j = ch * 8 + e;
            vals[e] = (j == gq || j == 33) ? lg : (u16)0;
        }
        *(uintx4*)(Qe + (size_t)ri * 128 + (8 + ch) * 8) = *(uintx4*)vals;
    } else if (bid < 3072) {
        int ri = (bid - 2048) * 32 + (tid >> 3);
        int bh = ri >> 11, l = ri & 2047;
        int b = bh >> 3, h = bh & 7;
        int ch = tid & 7;
        int gk = gap_ids[b * 2048 + l];
        int did = dur_ids[b * 2048 + l];
        int msk = amask[b * 2048 + l];
        float kval = msk ? dur_emb[did * 8 + h] : -1e9f;
        u16 vals[8];
        for (int e = 0; e < 8; e++) {
            int j = ch * 8 + e;
            float v;
            if (j <= 32) { int d = j - gk; d = d < 0 ? -d : d; v = gap_emb[d * 8 + h]; }
            else if (j == 33) v = kval;
            else v = 0.f;
            vals[e] = f2bf(v);
        }
        int phys = 8 | (ch ^ (l & 7));
        *(uintx4*)(Ke + (size_t)ri * 128 + phys * 8) = *(uintx4*)vals;
    } else {
        int bid2 = bid - 3072;
        int mat = bid2 >> 6, t8 = bid2 & 63;
        int n0 = (t8 & 7) * 64, k0 = (t8 >> 3) * 64;
        const float* W = (mat == 0) ? Wq : (mat == 1) ? Wk : (mat == 2) ? Wv : Wo;
        u16* WT = (mat == 0) ? WqT : (mat == 1) ? WkT : (mat == 2) ? WvT : WoT;
        int r = tid >> 4, cq = tid & 15;
        for (int rr = 0; rr < 4; rr++) {
            int row = r + rr * 16;
            floatx4 s = *(const floatx4*)&W[(size_t)(k0 + row) * 512 + n0 + cq * 4];
            T[cq * 4 + 0][row] = f2bf(s.x);
            T[cq * 4 + 1][row] = f2bf(s.y);
            T[cq * 4 + 2][row] = f2bf(s.z);
            T[cq * 4 + 3][row] = f2bf(s.w);
        }
        __syncthreads();
        for (int p = 0; p < 2; p++) {
            int idx = p * 256 + tid;
            int c = idx >> 3, ch = idx & 7;
            *(uintx4*)&WT[(size_t)(n0 + c) * 512 + k0 + ch * 8] = *(const uintx4*)&T[c][ch * 8];
        }
    }
}

// ---------------- fused QKV projection GEMM, 128x128 tile (2 heads), async dbuf ----------
// grid (32, 12): mat = gy>>2, head-pair hp = gy&3 (heads 2hp, 2hp+1).
__global__ __launch_bounds__(256) void gemm_qkv(
        const u16* __restrict__ Xb,
        const u16* __restrict__ WqT, const u16* __restrict__ WkT, const u16* __restrict__ WvT,
        const float* __restrict__ bq, const float* __restrict__ bk, const float* __restrict__ bv,
        u16* __restrict__ Qe, u16* __restrict__ Ke, u16* __restrict__ Vt) {
    __shared__ u16 smem[2][16384];              // per buf: As[0:8192) | Bs[8192:16384)

    int tid = threadIdx.x;
    int m0 = blockIdx.x * 128;
    int gy = blockIdx.y;
    int mat = gy >> 2, hp = gy & 3;
    int ncol0 = hp * 128;
    const u16* Bt = (mat == 0) ? WqT : (mat == 1) ? WkT : WvT;
    const float* bias = (mat == 0) ? bq : (mat == 1) ? bk : bv;

    int lane = tid & 63, w = tid >> 6, lo = lane & 15, hi = lane >> 4;
    int wm = w >> 1, wn = w & 1;
    floatx4 acc[4][4] = {};

#define QSTAGE(KB, BUF) do {                                                            \
        int k0_ = (KB) * 64;                                                            \
        for (int it = 0; it < 4; it++) {                                                \
            int c = it * 256 + tid;                                                     \
            int row = c >> 3, ch = c & 7;                                               \
            gl_lds16((const char*)Xb + ((size_t)(m0 + row) * 512 + k0_) * 2 + ch * 16,  \
                     (char*)(smem[BUF]) + c * 16);                                      \
        }                                                                               \
        for (int it = 0; it < 4; it++) {                                                \
            int c = it * 256 + tid;                                                     \
            int row = c >> 3, ch = c & 7;                                               \
            gl_lds16((const char*)Bt + ((size_t)(ncol0 + row) * 512 + k0_) * 2 + ch * 16,\
                     (char*)(smem[BUF] + 8192) + c * 16);                               \
        }                                                                               \
    } while (0)

    QSTAGE(0, 0);
    for (int kb = 0; kb < 8; kb++) {
        DRAIN();
        __syncthreads();
        if (kb + 1 < 8) QSTAGE(kb + 1, (kb + 1) & 1);
        const u16* As = smem[kb & 1];
        const u16* Bs = smem[kb & 1] + 8192;
        for (int s = 0; s < 2; s++) {
            bf16x8 a[4], b[4];
            for (int i = 0; i < 4; i++)
                a[i] = ld_frag(&As[(64 * wm + 16 * i + lo) * 64 + s * 32 + hi * 8]);
            for (int j = 0; j < 4; j++)
                b[j] = ld_frag(&Bs[(64 * wn + 16 * j + lo) * 64 + s * 32 + hi * 8]);
            for (int i = 0; i < 4; i++)
                for (int j = 0; j < 4; j++)
                    acc[i][j] = MFMA16(a[i], b[j], acc[i][j]);
        }
    }
#undef QSTAGE

    int bb = m0 >> 11, l0 = m0 & 2047;
    __syncthreads();                            // all waves past last compute; reuse smem

    if (mat < 2) {
        u16* Ot = &smem[0][0];                  // [128 rows][pitch 144: two 72-halves]
        for (int j = 0; j < 4; j++) {
            int c64 = 16 * j + lo;
            float bval = bias[ncol0 + 64 * wn + c64];
            for (int i = 0; i < 4; i++) {
                int row = 64 * wm + 16 * i + 4 * hi;
                for (int r = 0; r < 4; r++) {
                    float v = acc[i][j][r] + bval;
                    if (mat == 0) v *= QSCALE;
                    Ot[(row + r) * 144 + wn * 72 + c64] = f2bf(v);
                }
            }
        }
        __syncthreads();
        for (int p = 0; p < 8; p++) {
            int cc = p * 256 + tid;             // 2048 chunks: (row 0..127) x (h2,ch)
            int row = cc >> 4, hcb = cc & 15;
            int h2 = hcb >> 3, ch = hcb & 7;
            int lrow = l0 + row;
            size_t rowi = (size_t)(bb * 8 + 2 * hp + h2) * 2048 + lrow;
            int ch2 = (mat == 1) ? (ch ^ (lrow & 7)) : ch;
            u16* dstp = (mat == 0) ? Qe : Ke;
            *(uintx4*)(dstp + rowi * 128 + ch2 * 8) =
                *(const uintx4*)(Ot + row * 144 + h2 * 72 + ch * 8);
        }
    } else {
        // V: stage transposed [dcs 0..127][128 keys]; stream in PV-fragment order:
        // key = 64g64+32g+16p+4q+r -> chunk m_log = 4g+q (content [p*4+r]), phys = m_log^(dc&7)
        u16* Ot = &smem[0][0];                  // [128][pitch 136]
        for (int j = 0; j < 4; j++) {
            int dcs = 64 * wn + 16 * j + lo;    // 0..127 (two heads' d-slots)
            float bval = bias[ncol0 + dcs];
            for (int i = 0; i < 4; i++) {
                int row = 64 * wm + 16 * i + 4 * hi;
                for (int r = 0; r < 4; r++)
                    Ot[dcs * 136 + row + r] = f2bf(acc[i][j][r] + bval);
            }
        }
        __syncthreads();
        for (int p = 0; p < 8; p++) {
            int cc4 = p * 256 + tid;            // 2048: (dcs 0..127) x (16B chunk 0..15)
            int dcs = cc4 >> 4, c16 = cc4 & 15;
            int g64 = c16 >> 3, phys = c16 & 7;
            int h2 = dcs >> 6, dc = dcs & 63;
            int mlog = phys ^ (dc & 7);
            int g = mlog >> 2, q = mlog & 3;
            int base = g64 * 64 + 32 * g + 4 * q;
            uintx2 lo4 = *(const uintx2*)(Ot + dcs * 136 + base);
            uintx2 hi4 = *(const uintx2*)(Ot + dcs * 136 + base + 16);
            uintx4 t; t.x = lo4.x; t.y = lo4.y; t.z = hi4.x; t.w = hi4.y;
            size_t dst = ((size_t)(bb * 8 + 2 * hp + h2) * 64 + dc) * 2048
                         + l0 + g64 * 64 + phys * 8;
            *(uintx4*)(Vt + dst) = t;
        }
    }
}

// ---------------- flash attention: 128 queries/block, shared K/V frags, async dbuf + drain
// grid (16, 16, 2); block 256 = 4 waves; bf16 partials out
__global__ __launch_bounds__(256, 3) void flash_attn(
        const u16* __restrict__ Qe, const u16* __restrict__ Ke, const u16* __restrict__ Vt,
        u16* __restrict__ Opart, float* __restrict__ Lpart) {
    __shared__ u16 Ks[2][64 * 128];   // 2 x 16 KB
    __shared__ u16 Vs[2][64 * 64];    // 2 x 8 KB

    int tid = threadIdx.x, lane = tid & 63, w = tid >> 6, lo = lane & 15, hi = lane >> 4;
    int qt2 = blockIdx.x, bh = blockIdx.y, sp = blockIdx.z;
    int sw = lo & 7;

    bf16x8 bq_[2][4];
    for (int g = 0; g < 2; g++) {
        size_t qrow = ((size_t)bh * 2048 + qt2 * 128 + g * 64 + 16 * w + lo) * 128;
        for (int kc = 0; kc < 4; kc++) bq_[g][kc] = ld_frag(&Qe[qrow + kc * 32 + hi * 8]);
    }

    floatx4 O[2][4] = {};       // O[g][u][r]: query grp g (4hi+r), d=16u+lo
    floatx4 Lacc[2] = {};
    uintx4 onesu; onesu.x = 0x3F803F80u; onesu.y = 0x3F803F80u; onesu.z = 0x3F803F80u; onesu.w = 0x3F803F80u;
    bf16x8 ones = __builtin_bit_cast(bf16x8, onesu);

    const u16* KeB = Ke + (size_t)bh * 2048 * 128;
    const u16* VtB = Vt + (size_t)bh * 64 * 2048;

    int kbeg = sp * 16, kend = kbeg + 16;

#define STAGE(KT, BUF) do {                                                        \
        int k0_ = (KT) * 64;                                                       \
        const char* gk_ = (const char*)(KeB + (size_t)k0_ * 128);                  \
        char* lk_ = (char*)Ks[BUF];                                                \
        for (int r2 = 0; r2 < 4; r2++)                                             \
            gl_lds16(gk_ + r2 * 4096 + tid * 16, lk_ + r2 * 4096 + tid * 16);      \
        for (int p2 = 0; p2 < 2; p2++) {                                           \
            int c_ = p2 * 256 + tid;                                               \
            int row_ = c_ >> 3, ch_ = c_ & 7;                                      \
            gl_lds16((const char*)(VtB + (size_t)row_ * 2048 + k0_) + ch_ * 16,    \
                     (char*)Vs[BUF] + c_ * 16);                                    \
        }                                                                          \
    } while (0)

    int cur = 0;
    STAGE(kbeg, 0);
    for (int kt = kbeg; kt < kend; kt++) {
        DRAIN();                                // buf[cur]'s DMAs guaranteed landed
        __syncthreads();
        if (kt + 1 < kend) STAGE(kt + 1, cur ^ 1);

        const u16* Ksc = Ks[cur];
        const u16* Vsc = Vs[cur];

        // S^T = K * Q^T for both query groups (K frags shared)
        floatx4 sf[2][4] = {};
        for (int t = 0; t < 4; t++) {
            const u16* krow = &Ksc[(16 * t + lo) * 128];
            for (int kc = 0; kc < 4; kc++) {
                int cc = kc * 4 + hi;
                int pc = (cc & 8) | ((cc & 7) ^ sw);
                bf16x8 a = ld_frag(&krow[pc * 8]);
                sf[0][t] = MFMA16(a, bq_[0][kc], sf[0][t]);
                sf[1][t] = MFMA16(a, bq_[1][kc], sf[1][t]);
            }
        }

        // P = 2^S, pack to bf16 (round-half-up); af[g][tp] = A-frags
        bf16x8 af[2][2];
        for (int g = 0; g < 2; g++) {
            u32 pk[4][2];
            for (int t = 0; t < 4; t++) {
                float p0 = EXP2F(sf[g][t][0]);
                float p1 = EXP2F(sf[g][t][1]);
                float p2 = EXP2F(sf[g][t][2]);
                float p3 = EXP2F(sf[g][t][3]);
                u32 u0 = __builtin_bit_cast(u32, p0) + 0x8000u;
                u32 u1 = __builtin_bit_cast(u32, p1) + 0x8000u;
                u32 u2 = __builtin_bit_cast(u32, p2) + 0x8000u;
                u32 u3 = __builtin_bit_cast(u32, p3) + 0x8000u;
                pk[t][0] = __builtin_amdgcn_perm(u1, u0, 0x07060302);
                pk[t][1] = __builtin_amdgcn_perm(u3, u2, 0x07060302);
            }
            for (int tp = 0; tp < 2; tp++) {
                uintx4 av;
                av.x = pk[2 * tp][0]; av.y = pk[2 * tp][1];
                av.z = pk[2 * tp + 1][0]; av.w = pk[2 * tp + 1][1];
                af[g][tp] = __builtin_bit_cast(bf16x8, av);
            }
        }

        // O += P V (V frags shared across groups; one b128 per frag) ; l via ones-MFMA
        for (int tp = 0; tp < 2; tp++) {
            Lacc[0] = MFMA16(af[0][tp], ones, Lacc[0]);
            Lacc[1] = MFMA16(af[1][tp], ones, Lacc[1]);
            for (int u = 0; u < 4; u++) {
                const u16* vrow = &Vsc[(16 * u + lo) * 64];
                int m = (4 * tp + hi) ^ sw;
                bf16x8 bv = ld_frag(&vrow[m * 8]);
                O[0][u] = MFMA16(af[0][tp], bv, O[0][u]);
                O[1][u] = MFMA16(af[1][tp], bv, O[1][u]);
            }
        }
        cur ^= 1;
    }
#undef STAGE

    for (int g = 0; g < 2; g++) {
        int qt = 2 * qt2 + g;
        size_t obase = (((size_t)sp * 16 + bh) * 32 + qt) * 4096;
        for (int u = 0; u < 4; u++)
            for (int r = 0; r < 4; r++)
                Opart[obase + (size_t)(16 * w + 4 * hi + r) * 64 + 16 * u + lo] =
                    f2bf(O[g][u][r]);
        if (lo == 0) {
            size_t lbase = (((size_t)sp * 16 + bh) * 32 + qt) * 64;
            for (int r = 0; r < 4; r++) Lpart[lbase + 16 * w + 4 * hi + r] = Lacc[g][r];
        }
    }
}

// ---------------- combine the 2 key-splits (bf16 partials), normalize, cast to bf16 -------
__global__ __launch_bounds__(256) void combine_kernel(const u16* __restrict__ Opart,
                                                      const float* __restrict__ Lpart,
                                                      u16* __restrict__ Ob) {
    int idx = blockIdx.x * 256 + threadIdx.x;   // 0..524287, 4 d-elems each
    int d4 = idx & 15;
    int q = (idx >> 4) & 2047;
    int bh = idx >> 15;
    int qt = q >> 6, qr = q & 63;
    size_t b0 = ((size_t)bh * 32 + qt) * 4096 + qr * 64 + d4 * 4;
    uintx2 a0 = *(const uintx2*)&Opart[b0];
    uintx2 a1 = *(const uintx2*)&Opart[b0 + 2097152];
    size_t lb = ((size_t)bh * 32 + qt) * 64 + qr;
    float rl = 1.0f / (Lpart[lb] + Lpart[lb + 32768]);
    float s0 = bflo2f(a0.x) + bflo2f(a1.x);
    float s1 = bfhi2f(a0.x) + bfhi2f(a1.x);
    float s2 = bflo2f(a0.y) + bflo2f(a1.y);
    float s3 = bfhi2f(a0.y) + bfhi2f(a1.y);
    uintx2 pk2;
    pk2.x = f2bf(s0 * rl) | ((u32)f2bf(s1 * rl) << 16);
    pk2.y = f2bf(s2 * rl) | ((u32)f2bf(s3 * rl) << 16);
    int bb = bh >> 3, h = bh & 7;
    *(uintx2*)&Ob[((size_t)(bb * 2048 + q)) * 512 + h * 64 + d4 * 4] = pk2;
}

// ---------------- output projection GEMM, 64x64 tile, async dbuf (bf16 in, fp32 out) ------
__global__ __launch_bounds__(256) void gemm_out(
        const u16* __restrict__ Ob, const u16* __restrict__ WoT,
        const float* __restrict__ bo, float* __restrict__ out) {
    __shared__ u16 smem[2][8192];               // per buf: As[0:4096) | Bs[4096:8192)
    int tid = threadIdx.x;
    int m0 = blockIdx.x * 64;
    int n0 = blockIdx.y * 64;
    int lane = tid & 63, w = tid >> 6, lo = lane & 15, hi = lane >> 4;
    floatx4 acc[4] = {};

#define OSTAGE(KB, BUF) do {                                                            \
        int k0_ = (KB) * 64;                                                            \
        for (int it = 0; it < 2; it++) {                                                \
            int c = it * 256 + tid;                                                     \
            int row = c >> 3, ch = c & 7;                                               \
            gl_lds16((const char*)Ob + ((size_t)(m0 + row) * 512 + k0_) * 2 + ch * 16,  \
                     (char*)(smem[BUF]) + c * 16);                                      \
        }                                                                               \
        for (int it = 0; it < 2; it++) {                                                \
            int c = it * 256 + tid;                                                     \
            int row = c >> 3, ch = c & 7;                                               \
            gl_lds16((const char*)WoT + ((size_t)(n0 + row) * 512 + k0_) * 2 + ch * 16, \
                     (char*)(smem[BUF] + 4096) + c * 16);                               \
        }                                                                               \
    } while (0)

    OSTAGE(0, 0);
    for (int kb = 0; kb < 8; kb++) {
        DRAIN();
        __syncthreads();
        if (kb + 1 < 8) OSTAGE(kb + 1, (kb + 1) & 1);
        const u16* As = smem[kb & 1];
        const u16* Bs = smem[kb & 1] + 4096;
        for (int s = 0; s < 2; s++) {
            bf16x8 a = ld_frag(&As[(16 * w + lo) * 64 + s * 32 + hi * 8]);
            for (int t = 0; t < 4; t++) {
                bf16x8 b = ld_frag(&Bs[(16 * t + lo) * 64 + s * 32 + hi * 8]);
                acc[t] = MFMA16(a, b, acc[t]);
            }
        }
    }
#undef OSTAGE

    for (int t = 0; t < 4; t++) {
        int n = n0 + 16 * t + lo;
        float bval = bo[n];
        for (int r = 0; r < 4; r++) {
            int mrow = m0 + 16 * w + 4 * hi + r;
            out[(size_t)mrow * 512 + n] = acc[t][r] + bval;
        }
    }
}

extern "C" void kernel_launch(void* const* d_in, const int* in_sizes, int n_in,
                              void* d_out, int out_size, void* d_ws, size_t ws_size,
                              hipStream_t stream) {
    const float* x     = (const float*)d_in[0];
    const int*   amask = (const int*)d_in[1];
    const int*   gids  = (const int*)d_in[2];
    const int*   dids  = (const int*)d_in[3];
    const float* Wq    = (const float*)d_in[4];
    const float* bq    = (const float*)d_in[5];
    const float* Wk    = (const float*)d_in[6];
    const float* bk    = (const float*)d_in[7];
    const float* Wv    = (const float*)d_in[8];
    const float* bv    = (const float*)d_in[9];
    const float* Wo    = (const float*)d_in[10];
    const float* bo    = (const float*)d_in[11];
    const float* gap_emb = (const float*)d_in[12];
    const float* dur_emb = (const float*)d_in[13];
    float* out = (float*)d_out;

    char* ws = (char*)d_ws;
    u16*   Qe    = (u16*)(ws + 0);            // 8.4 MB
    u16*   Ke    = (u16*)(ws + 8388608);      // 8.4 MB
    u16*   Vt    = (u16*)(ws + 16777216);     // 4.2 MB
    u16*   Opart = (u16*)(ws + 20971520);     // 8.4 MB (2 splits, bf16)
    float* Lpart = (float*)(ws + 29360128);   // 0.26 MB
    u16*   Ob    = (u16*)(ws + 29622272);     // 4.2 MB
    u16*   WoT   = (u16*)(ws + 33816576);     // 0.5 MB
    // stage-1 scratch aliased inside Opart (dead before flash_attn writes it)
    u16*   Xb    = (u16*)(ws + 20971520);     // 4.2 MB
    u16*   WqT   = (u16*)(ws + 25165824);
    u16*   WkT   = (u16*)(ws + 25690112);
    u16*   WvT   = (u16*)(ws + 26214400);

    hipLaunchKernelGGL(prep_kernel, dim3(3328), dim3(256), 0, stream,
                       x, gids, dids, amask, gap_emb, dur_emb,
                       Wq, Wk, Wv, Wo, Xb, Qe, Ke, WqT, WkT, WvT, WoT);
    hipLaunchKernelGGL(gemm_qkv, dim3(32, 12), dim3(256), 0, stream,
                       Xb, WqT, WkT, WvT, bq, bk, bv, Qe, Ke, Vt);
    hipLaunchKernelGGL(flash_attn, dim3(16, 16, 2), dim3(256), 0, stream,
                       Qe, Ke, Vt, Opart, Lpart);
    hipLaunchKernelGGL(combine_kernel, dim3(2048), dim3(256), 0, stream,
                       Opart, Lpart, Ob);
    hipLaunchKernelGGL(gemm_out, dim3(64, 8), dim3(256), 0, stream,
                       Ob, WoT, bo, out);
}